// Round 1
// baseline (406.662 us; speedup 1.0000x reference)
//
#include <hip/hip_runtime.h>
#include <cstdint>
#include <cstddef>

typedef unsigned short u16;
typedef short bf16x8 __attribute__((ext_vector_type(8)));
typedef unsigned short u16x8 __attribute__((ext_vector_type(8)));
typedef float f32x4 __attribute__((ext_vector_type(4)));

__device__ __forceinline__ u16 f2bf(float x) {
    union { float f; unsigned int u; } v; v.f = x;
    unsigned int u = v.u;
    unsigned int r = (u + 0x7fffu + ((u >> 16) & 1u)) >> 16;
    return (u16)r;
}

// ---------------- cast fp32 -> bf16 (vectorized, grid-stride) ----------------
__global__ void cast_f32_bf16(const float* __restrict__ in, u16* __restrict__ out, int n) {
    int i = (blockIdx.x * blockDim.x + threadIdx.x) * 4;
    int stride = gridDim.x * blockDim.x * 4;
    for (; i < n; i += stride) {
        float4 f = *reinterpret_cast<const float4*>(in + i);
        ushort4 o;
        o.x = f2bf(f.x); o.y = f2bf(f.y); o.z = f2bf(f.z); o.w = f2bf(f.w);
        *reinterpret_cast<ushort4*>(out + i) = o;
    }
}

// ---------------- bf16 GEMM: C[M,N] = A[M,K] @ B[N,K]^T ----------------
// 128x128 tile, BK=32, 4 waves (2x2), each wave 64x64 via 4x4 16x16x32 MFMAs.
template <typename OutT>
__global__ __launch_bounds__(256) void gemm_bt(const u16* __restrict__ A,
                                               const u16* __restrict__ Bw,
                                               OutT* __restrict__ C,
                                               int M, int N, int K) {
    __shared__ u16 As[128][40];  // 40-ushort stride = 80B = 5*16B (aligned b128 reads)
    __shared__ u16 Bs[128][40];

    const int tid  = threadIdx.x;
    const int m0   = blockIdx.x * 128;
    const int n0   = blockIdx.y * 128;
    const int wid  = tid >> 6;
    const int lane = tid & 63;
    const int wr   = (wid >> 1) * 64;
    const int wc   = (wid & 1) * 64;

    const int lr = tid >> 2;        // 0..63
    const int lc = (tid & 3) * 8;   // 0,8,16,24

    f32x4 acc[4][4];
#pragma unroll
    for (int i = 0; i < 4; ++i)
#pragma unroll
        for (int j = 0; j < 4; ++j) acc[i][j] = f32x4{0.f, 0.f, 0.f, 0.f};

    const int fr = lane & 15;
    const int ko = (lane >> 4) * 8;

    for (int k0 = 0; k0 < K; k0 += 32) {
        *reinterpret_cast<u16x8*>(&As[lr][lc]) =
            *reinterpret_cast<const u16x8*>(&A[(size_t)(m0 + lr) * K + k0 + lc]);
        *reinterpret_cast<u16x8*>(&As[lr + 64][lc]) =
            *reinterpret_cast<const u16x8*>(&A[(size_t)(m0 + lr + 64) * K + k0 + lc]);
        *reinterpret_cast<u16x8*>(&Bs[lr][lc]) =
            *reinterpret_cast<const u16x8*>(&Bw[(size_t)(n0 + lr) * K + k0 + lc]);
        *reinterpret_cast<u16x8*>(&Bs[lr + 64][lc]) =
            *reinterpret_cast<const u16x8*>(&Bw[(size_t)(n0 + lr + 64) * K + k0 + lc]);
        __syncthreads();

        bf16x8 af[4], bfr[4];
#pragma unroll
        for (int mf = 0; mf < 4; ++mf)
            af[mf] = *reinterpret_cast<const bf16x8*>(&As[wr + mf * 16 + fr][ko]);
#pragma unroll
        for (int nf = 0; nf < 4; ++nf)
            bfr[nf] = *reinterpret_cast<const bf16x8*>(&Bs[wc + nf * 16 + fr][ko]);
#pragma unroll
        for (int mf = 0; mf < 4; ++mf)
#pragma unroll
            for (int nf = 0; nf < 4; ++nf)
                acc[mf][nf] = __builtin_amdgcn_mfma_f32_16x16x32_bf16(
                    af[mf], bfr[nf], acc[mf][nf], 0, 0, 0);
        __syncthreads();
    }

    const int rq = (lane >> 4) * 4;
#pragma unroll
    for (int mf = 0; mf < 4; ++mf)
#pragma unroll
        for (int nf = 0; nf < 4; ++nf)
#pragma unroll
            for (int i = 0; i < 4; ++i) {
                int row = m0 + wr + mf * 16 + rq + i;
                int col = n0 + wc + nf * 16 + fr;
                float v = acc[mf][nf][i];
                if constexpr (sizeof(OutT) == 2)
                    C[(size_t)row * N + col] = (OutT)f2bf(v);
                else
                    C[(size_t)row * N + col] = (OutT)v;
            }
}

// ---------------- causal flash attention ----------------
// Q,K,V,Y layout: [B*T, D] bf16, head h at cols h*64..h*64+63.
// Block: 256 threads, 64 Q rows (wave w owns rows w*16..w*16+15), KV tiles of 64.
__global__ __launch_bounds__(256) void attn_fwd(const u16* __restrict__ Q,
                                                const u16* __restrict__ Kg,
                                                const u16* __restrict__ Vg,
                                                u16* __restrict__ Y) {
    constexpr int Dm = 1024, dh = 64, Tt = 2048;
    const int qt   = blockIdx.x;          // q tile (64 rows)
    const int bh   = blockIdx.y;          // b*16 + h
    const int b    = bh >> 4;
    const int h    = bh & 15;
    const size_t base = (size_t)b * Tt * Dm + (size_t)h * dh;

    const int tid = threadIdx.x, w = tid >> 6, lane = tid & 63;
    const int q0  = qt * 64;

    __shared__ u16 Ks[64][72];       // K rows x d, 72-stride = 144B = 9*16B
    __shared__ u16 Vt[64][72];       // V transposed: [d][k]
    __shared__ u16 Ps[4][16][72];    // per-wave P staging

    const int fr = lane & 15;
    const int ko = (lane >> 4) * 8;
    const int rq = (lane >> 4) * 4;

    // Q fragments (held in registers across the whole loop)
    bf16x8 qf[2];
    const int qrow = q0 + w * 16 + fr;
#pragma unroll
    for (int kk = 0; kk < 2; ++kk)
        qf[kk] = *reinterpret_cast<const bf16x8*>(&Q[base + (size_t)qrow * Dm + kk * 32 + ko]);

    f32x4 o_acc[4];
#pragma unroll
    for (int i = 0; i < 4; ++i) o_acc[i] = f32x4{0.f, 0.f, 0.f, 0.f};
    float m_run[4], l_run[4];
#pragma unroll
    for (int i = 0; i < 4; ++i) { m_run[i] = -INFINITY; l_run[i] = 0.f; }

    const int sr = tid >> 2;        // 0..63
    const int sc = (tid & 3) * 8;   // 0,8,16,24

    for (int kt = 0; kt <= qt; ++kt) {
        const int k0 = kt * 64;
        // stage K (row-major) and V (transposed)
#pragma unroll
        for (int half = 0; half < 2; ++half) {
            const int c = sc + half * 32;
            u16x8 kv = *reinterpret_cast<const u16x8*>(&Kg[base + (size_t)(k0 + sr) * Dm + c]);
            *reinterpret_cast<u16x8*>(&Ks[sr][c]) = kv;
            u16x8 vv = *reinterpret_cast<const u16x8*>(&Vg[base + (size_t)(k0 + sr) * Dm + c]);
#pragma unroll
            for (int j = 0; j < 8; ++j) Vt[c + j][sr] = vv[j];
        }
        __syncthreads();

        // S = Q @ K^T
        f32x4 s[4];
#pragma unroll
        for (int nf = 0; nf < 4; ++nf) s[nf] = f32x4{0.f, 0.f, 0.f, 0.f};
#pragma unroll
        for (int nf = 0; nf < 4; ++nf)
#pragma unroll
            for (int kk = 0; kk < 2; ++kk) {
                bf16x8 kf = *reinterpret_cast<const bf16x8*>(&Ks[nf * 16 + fr][kk * 32 + ko]);
                s[nf] = __builtin_amdgcn_mfma_f32_16x16x32_bf16(qf[kk], kf, s[nf], 0, 0, 0);
            }

        // scale + causal mask + row max
        float pm[4];
#pragma unroll
        for (int i = 0; i < 4; ++i) pm[i] = -INFINITY;
#pragma unroll
        for (int nf = 0; nf < 4; ++nf)
#pragma unroll
            for (int i = 0; i < 4; ++i) {
                float sv = s[nf][i] * 0.125f;
                if (kt == qt) {
                    int kc = k0 + nf * 16 + fr;
                    int qr = q0 + w * 16 + rq + i;
                    if (kc > qr) sv = -INFINITY;
                }
                s[nf][i] = sv;
                pm[i] = fmaxf(pm[i], sv);
            }
#pragma unroll
        for (int mask = 1; mask < 16; mask <<= 1)
#pragma unroll
            for (int i = 0; i < 4; ++i) pm[i] = fmaxf(pm[i], __shfl_xor(pm[i], mask));

        float mn[4], fsc[4], ps[4];
#pragma unroll
        for (int i = 0; i < 4; ++i) {
            mn[i]  = fmaxf(m_run[i], pm[i]);
            fsc[i] = __expf(m_run[i] - mn[i]);
            ps[i]  = 0.f;
        }
#pragma unroll
        for (int nf = 0; nf < 4; ++nf)
#pragma unroll
            for (int i = 0; i < 4; ++i) {
                float p = __expf(s[nf][i] - mn[i]);
                s[nf][i] = p;
                ps[i] += p;
            }
#pragma unroll
        for (int mask = 1; mask < 16; mask <<= 1)
#pragma unroll
            for (int i = 0; i < 4; ++i) ps[i] += __shfl_xor(ps[i], mask);
#pragma unroll
        for (int i = 0; i < 4; ++i) {
            l_run[i] = l_run[i] * fsc[i] + ps[i];
            m_run[i] = mn[i];
        }
#pragma unroll
        for (int nf = 0; nf < 4; ++nf)
#pragma unroll
            for (int i = 0; i < 4; ++i) o_acc[nf][i] *= fsc[i];

        // P -> LDS (bf16), then PV
#pragma unroll
        for (int nf = 0; nf < 4; ++nf)
#pragma unroll
            for (int i = 0; i < 4; ++i)
                Ps[w][rq + i][nf * 16 + fr] = f2bf(s[nf][i]);

#pragma unroll
        for (int nf = 0; nf < 4; ++nf)
#pragma unroll
            for (int kk = 0; kk < 2; ++kk) {
                bf16x8 pf = *reinterpret_cast<const bf16x8*>(&Ps[w][fr][kk * 32 + ko]);
                bf16x8 vf = *reinterpret_cast<const bf16x8*>(&Vt[nf * 16 + fr][kk * 32 + ko]);
                o_acc[nf] = __builtin_amdgcn_mfma_f32_16x16x32_bf16(pf, vf, o_acc[nf], 0, 0, 0);
            }
        __syncthreads();
    }

    // epilogue: divide by l, store bf16
#pragma unroll
    for (int nf = 0; nf < 4; ++nf)
#pragma unroll
        for (int i = 0; i < 4; ++i) {
            float val = o_acc[nf][i] / l_run[i];
            int r = q0 + w * 16 + rq + i;
            Y[base + (size_t)r * Dm + nf * 16 + fr] = f2bf(val);
        }
}

extern "C" void kernel_launch(void* const* d_in, const int* in_sizes, int n_in,
                              void* d_out, int out_size, void* d_ws, size_t ws_size,
                              hipStream_t stream) {
    const float* x  = (const float*)d_in[0];
    const float* Wq = (const float*)d_in[1];
    const float* Wk = (const float*)d_in[2];
    const float* Wv = (const float*)d_in[3];
    const float* Wo = (const float*)d_in[4];

    constexpr int B = 4, T = 2048, D = 1024;
    constexpr int M = B * T;                 // 8192
    const int nx = in_sizes[0];              // 8388608
    const int nw = in_sizes[1];              // 1048576

    char* ws = (char*)d_ws;
    const size_t SEG = (size_t)M * D * 2;    // 16 MB per activation buffer
    u16* xb  = (u16*)(ws + 0 * SEG);
    u16* qb  = (u16*)(ws + 1 * SEG);
    u16* kb  = (u16*)(ws + 2 * SEG);
    u16* vb  = (u16*)(ws + 3 * SEG);
    u16* yb  = (u16*)(ws + 4 * SEG);
    u16* wqb = (u16*)(ws + 5 * SEG + 0 * (size_t)nw * 2);
    u16* wkb = (u16*)(ws + 5 * SEG + 1 * (size_t)nw * 2);
    u16* wvb = (u16*)(ws + 5 * SEG + 2 * (size_t)nw * 2);
    u16* wob = (u16*)(ws + 5 * SEG + 3 * (size_t)nw * 2);

    cast_f32_bf16<<<2048, 256, 0, stream>>>(x, xb, nx);
    cast_f32_bf16<<<512, 256, 0, stream>>>(Wq, wqb, nw);
    cast_f32_bf16<<<512, 256, 0, stream>>>(Wk, wkb, nw);
    cast_f32_bf16<<<512, 256, 0, stream>>>(Wv, wvb, nw);
    cast_f32_bf16<<<512, 256, 0, stream>>>(Wo, wob, nw);

    dim3 gg(M / 128, D / 128);
    gemm_bt<u16><<<gg, 256, 0, stream>>>(xb, wqb, qb, M, D, D);
    gemm_bt<u16><<<gg, 256, 0, stream>>>(xb, wkb, kb, M, D, D);
    gemm_bt<u16><<<gg, 256, 0, stream>>>(xb, wvb, vb, M, D, D);

    attn_fwd<<<dim3(T / 64, B * 16), 256, 0, stream>>>(qb, kb, vb, yb);

    gemm_bt<float><<<gg, 256, 0, stream>>>(yb, wob, (float*)d_out, M, D, D);
}

// Round 2
// 373.549 us; speedup vs baseline: 1.0886x; 1.0886x over previous
//
#include <hip/hip_runtime.h>
#include <cstdint>
#include <cstddef>

typedef unsigned short u16;
typedef short bf16x8 __attribute__((ext_vector_type(8)));
typedef unsigned short u16x8 __attribute__((ext_vector_type(8)));
typedef float f32x4 __attribute__((ext_vector_type(4)));

__device__ __forceinline__ u16 f2bf(float x) {
    union { float f; unsigned int u; } v; v.f = x;
    unsigned int u = v.u;
    unsigned int r = (u + 0x7fffu + ((u >> 16) & 1u)) >> 16;
    return (u16)r;
}

// async global->LDS, 16B per lane. dest = wave-uniform base; lane i lands at base + i*16B.
__device__ __forceinline__ void load_lds16(const void* g, void* l) {
    __builtin_amdgcn_global_load_lds((const __attribute__((address_space(1))) void*)g,
                                     (__attribute__((address_space(3))) void*)l, 16, 0, 0);
}

// ---------------- cast fp32 -> bf16 ----------------
__global__ void cast_f32_bf16(const float* __restrict__ in, u16* __restrict__ out, int n) {
    int i = (blockIdx.x * blockDim.x + threadIdx.x) * 4;
    int stride = gridDim.x * blockDim.x * 4;
    for (; i < n; i += stride) {
        float4 f = *reinterpret_cast<const float4*>(in + i);
        ushort4 o;
        o.x = f2bf(f.x); o.y = f2bf(f.y); o.z = f2bf(f.z); o.w = f2bf(f.w);
        *reinterpret_cast<ushort4*>(out + i) = o;
    }
}

// ---------------- bf16 GEMM: C[M,N] = A[M,K] @ B[N,K]^T ----------------
// MODE 0: fp32 output to outp, row stride N.
// MODE 1: merged QKV. n0<2048 -> bf16 to qk (row stride 2048). n0>=2048 -> V,
//         written TRANSPOSED to vtg[b*1024 + (n-2048)][2048] via LDS restage.
template <int MODE>
__global__ __launch_bounds__(256) void gemm_bt(const u16* __restrict__ A,
                                               const u16* __restrict__ Bw,
                                               void* __restrict__ outp,
                                               u16* __restrict__ vtg,
                                               int M, int N, int K) {
    __shared__ u16 smem[16384];              // 32KB: As[0..4095], Bs[4096..8191]; Cst reuses all
    u16* As = smem;
    u16* Bs = smem + 4096;

    const int tid  = threadIdx.x;
    const int m0   = blockIdx.x * 128;
    const int n0   = blockIdx.y * 128;
    const int wid  = tid >> 6;
    const int lane = tid & 63;
    const int wr   = (wid >> 1) * 64;
    const int wc   = (wid & 1) * 64;
    const int fr   = lane & 15;
    const int ko   = (lane >> 4) * 8;
    const int rq   = (lane >> 4) * 4;

    f32x4 acc[4][4];
#pragma unroll
    for (int i = 0; i < 4; ++i)
#pragma unroll
        for (int j = 0; j < 4; ++j) acc[i][j] = f32x4{0.f, 0.f, 0.f, 0.f};

    const int lr4 = lane >> 2;   // 0..15
    const int ls  = lane & 3;    // slot (8 u16)

    for (int k0 = 0; k0 < K; k0 += 32) {
#pragma unroll
        for (int t = 0; t < 2; ++t) {
            const int qtr = wid * 2 + t;
            const int r   = qtr * 16 + lr4;
            load_lds16(&A[(size_t)(m0 + r) * K + k0 + ls * 8], &As[qtr * 512]);
            load_lds16(&Bw[(size_t)(n0 + r) * K + k0 + ls * 8], &Bs[qtr * 512]);
        }
        __syncthreads();

        bf16x8 af[4], bfr[4];
#pragma unroll
        for (int mf = 0; mf < 4; ++mf)
            af[mf] = *reinterpret_cast<const bf16x8*>(&As[(wr + mf * 16 + fr) * 32 + ko]);
#pragma unroll
        for (int nf = 0; nf < 4; ++nf)
            bfr[nf] = *reinterpret_cast<const bf16x8*>(&Bs[(wc + nf * 16 + fr) * 32 + ko]);
#pragma unroll
        for (int mf = 0; mf < 4; ++mf)
#pragma unroll
            for (int nf = 0; nf < 4; ++nf)
                acc[mf][nf] = __builtin_amdgcn_mfma_f32_16x16x32_bf16(
                    af[mf], bfr[nf], acc[mf][nf], 0, 0, 0);
        __syncthreads();
    }

    if constexpr (MODE == 0) {
        float* C = (float*)outp;
#pragma unroll
        for (int mf = 0; mf < 4; ++mf)
#pragma unroll
            for (int nf = 0; nf < 4; ++nf)
#pragma unroll
                for (int i = 0; i < 4; ++i)
                    C[(size_t)(m0 + wr + mf * 16 + rq + i) * N + n0 + wc + nf * 16 + fr] =
                        acc[mf][nf][i];
    } else {
        if (n0 < 2048) {
            u16* qk = (u16*)outp;
#pragma unroll
            for (int mf = 0; mf < 4; ++mf)
#pragma unroll
                for (int nf = 0; nf < 4; ++nf)
#pragma unroll
                    for (int i = 0; i < 4; ++i)
                        qk[(size_t)(m0 + wr + mf * 16 + rq + i) * 2048 + n0 + wc + nf * 16 + fr] =
                            f2bf(acc[mf][nf][i]);
        } else {
            // transpose 128x128 tile through LDS: Cst[n_local][m_local], swizzled rows of 256B
#pragma unroll
            for (int mf = 0; mf < 4; ++mf)
#pragma unroll
                for (int nf = 0; nf < 4; ++nf)
#pragma unroll
                    for (int i = 0; i < 4; ++i) {
                        const int nl = wc + nf * 16 + fr;
                        const int ml = wr + mf * 16 + rq + i;
                        smem[nl * 128 + ((((ml * 2) ^ ((nl & 15) << 4))) >> 1)] =
                            f2bf(acc[mf][nf][i]);
                    }
            __syncthreads();
            const int bb   = m0 >> 11;       // batch
            const int tloc = m0 & 2047;
#pragma unroll
            for (int p = 0; p < 8; ++p) {
                const int nl = (tid >> 4) + p * 16;
                const int sl = tid & 15;
                u16x8 v = *reinterpret_cast<const u16x8*>(
                    &smem[nl * 128 + ((((sl * 16) ^ ((nl & 15) << 4))) >> 1)]);
                *reinterpret_cast<u16x8*>(
                    &vtg[(size_t)(bb * 1024 + (n0 - 2048) + nl) * 2048 + tloc + sl * 8]) = v;
            }
        }
    }
}

// ---------------- causal flash attention ----------------
// qk: [B*T, 2048] bf16 (Q cols 0..1023, K cols 1024..2047), vtg: [B*16*64, 2048] = V^T per (b,h).
// Block: 256 thr, 128 Q rows (wave w owns rows w*32..w*32+31 as 2 row-frags), KV tiles of 64.
__global__ __launch_bounds__(256) void attn_fwd(const u16* __restrict__ qk,
                                                const u16* __restrict__ vtg,
                                                u16* __restrict__ Y) {
    constexpr int T = 2048, DQK = 2048, DOUT = 1024;
    const int qt = (int)gridDim.x - 1 - (int)blockIdx.x;   // long blocks launch first
    const int bh = blockIdx.y;
    const int b  = bh >> 4, h = bh & 15;
    const int tid = threadIdx.x, w = tid >> 6, lane = tid & 63;
    const int q0 = qt * 128;
    const int wqbase = q0 + w * 32;

    __shared__ u16 Ks[4096];    // [64 k][64 d] linear, slot^(row&7) swizzle
    __shared__ u16 Vs[4096];    // [64 d][64 k] linear, same swizzle
    __shared__ u16 Ps[8192];    // [w][rb][16][64], swizzled rows

    const int fr = lane & 15, g = lane >> 4;
    const int ko = g * 8, rq = g * 4;

    bf16x8 qf[2][2];
#pragma unroll
    for (int rb = 0; rb < 2; ++rb)
#pragma unroll
        for (int kk = 0; kk < 2; ++kk)
            qf[rb][kk] = *reinterpret_cast<const bf16x8*>(
                &qk[(size_t)(b * T + wqbase + rb * 16 + fr) * DQK + h * 64 + kk * 32 + ko]);

    f32x4 o[2][4];
    float mrun[2][4], lrun[2][4];
#pragma unroll
    for (int rb = 0; rb < 2; ++rb)
#pragma unroll
        for (int nf = 0; nf < 4; ++nf) o[rb][nf] = f32x4{0.f, 0.f, 0.f, 0.f};
#pragma unroll
    for (int rb = 0; rb < 2; ++rb)
#pragma unroll
        for (int i = 0; i < 4; ++i) { mrun[rb][i] = -INFINITY; lrun[rb][i] = 0.f; }

    const int sr8 = lane >> 3, ss = lane & 7;
    const int NT = 2 * qt + 2;
    constexpr float SCL = 1.4426950408889634f * 0.125f;   // log2(e)/sqrt(64)

    for (int kt = 0; kt < NT; ++kt) {
        const int k0 = kt * 64;
#pragma unroll
        for (int t = 0; t < 2; ++t) {
            const int qtr = w * 2 + t;
            const int r   = qtr * 8 + sr8;
            const int sc  = (ss ^ (r & 7)) * 8;            // pre-swizzled source slot
            load_lds16(&qk[(size_t)(b * T + k0 + r) * DQK + 1024 + h * 64 + sc], &Ks[qtr * 512]);
            load_lds16(&vtg[(size_t)(bh * 64 + r) * T + k0 + sc], &Vs[qtr * 512]);
        }
        __syncthreads();

        if (k0 <= wqbase + 31) {   // wave-uniform: skip fully-masked diagonal tiles
            bf16x8 kf[4][2];
#pragma unroll
            for (int nf = 0; nf < 4; ++nf)
#pragma unroll
                for (int kk = 0; kk < 2; ++kk) {
                    const int r = nf * 16 + fr;
                    kf[nf][kk] = *reinterpret_cast<const bf16x8*>(
                        &Ks[r * 64 + ((((g + kk * 4) * 16) ^ ((r & 7) << 4)) >> 1)]);
                }
            f32x4 s[2][4];
#pragma unroll
            for (int rb = 0; rb < 2; ++rb)
#pragma unroll
                for (int nf = 0; nf < 4; ++nf) s[rb][nf] = f32x4{0.f, 0.f, 0.f, 0.f};
#pragma unroll
            for (int rb = 0; rb < 2; ++rb)
#pragma unroll
                for (int nf = 0; nf < 4; ++nf)
#pragma unroll
                    for (int kk = 0; kk < 2; ++kk)
                        s[rb][nf] = __builtin_amdgcn_mfma_f32_16x16x32_bf16(
                            qf[rb][kk], kf[nf][kk], s[rb][nf], 0, 0, 0);

            float fsc[2][4];
#pragma unroll
            for (int rb = 0; rb < 2; ++rb) {
                const int rbase = wqbase + rb * 16;
                const bool dm = (k0 + 63 > rbase);
                float pm[4] = {-1e30f, -1e30f, -1e30f, -1e30f};
#pragma unroll
                for (int nf = 0; nf < 4; ++nf)
#pragma unroll
                    for (int i = 0; i < 4; ++i) {
                        float sv = s[rb][nf][i] * SCL;
                        if (dm) {
                            const int kc = k0 + nf * 16 + fr;
                            const int qr = rbase + rq + i;
                            if (kc > qr) sv = -1e30f;
                        }
                        s[rb][nf][i] = sv;
                        pm[i] = fmaxf(pm[i], sv);
                    }
#pragma unroll
                for (int mask = 1; mask < 16; mask <<= 1)
#pragma unroll
                    for (int i = 0; i < 4; ++i) pm[i] = fmaxf(pm[i], __shfl_xor(pm[i], mask));

                float mn[4], ps[4];
#pragma unroll
                for (int i = 0; i < 4; ++i) {
                    mn[i]       = fmaxf(mrun[rb][i], pm[i]);
                    fsc[rb][i]  = exp2f(mrun[rb][i] - mn[i]);
                    mrun[rb][i] = mn[i];
                    ps[i]       = 0.f;
                }
#pragma unroll
                for (int nf = 0; nf < 4; ++nf)
#pragma unroll
                    for (int i = 0; i < 4; ++i) {
                        float p = exp2f(s[rb][nf][i] - mn[i]);
                        s[rb][nf][i] = p;
                        ps[i] += p;
                    }
#pragma unroll
                for (int mask = 1; mask < 16; mask <<= 1)
#pragma unroll
                    for (int i = 0; i < 4; ++i) ps[i] += __shfl_xor(ps[i], mask);
#pragma unroll
                for (int i = 0; i < 4; ++i) lrun[rb][i] = lrun[rb][i] * fsc[rb][i] + ps[i];

                u16* pw = &Ps[(w * 2 + rb) * 1024];
#pragma unroll
                for (int nf = 0; nf < 4; ++nf)
#pragma unroll
                    for (int i = 0; i < 4; ++i) {
                        const int r = rq + i, c = nf * 16 + fr;
                        pw[r * 64 + ((((c * 2) ^ ((r & 7) << 4))) >> 1)] = f2bf(s[rb][nf][i]);
                    }
#pragma unroll
                for (int nf = 0; nf < 4; ++nf)
#pragma unroll
                    for (int i = 0; i < 4; ++i) o[rb][nf][i] *= fsc[rb][i];
            }

            bf16x8 vf[4][2];
#pragma unroll
            for (int nf = 0; nf < 4; ++nf)
#pragma unroll
                for (int kk = 0; kk < 2; ++kk) {
                    const int r = nf * 16 + fr;
                    vf[nf][kk] = *reinterpret_cast<const bf16x8*>(
                        &Vs[r * 64 + ((((g + kk * 4) * 16) ^ ((r & 7) << 4)) >> 1)]);
                }
#pragma unroll
            for (int rb = 0; rb < 2; ++rb) {
                const u16* pr = &Ps[(w * 2 + rb) * 1024];
                bf16x8 pa[2];
#pragma unroll
                for (int kk = 0; kk < 2; ++kk)
                    pa[kk] = *reinterpret_cast<const bf16x8*>(
                        &pr[fr * 64 + ((((g + kk * 4) * 16) ^ ((fr & 7) << 4)) >> 1)]);
#pragma unroll
                for (int nf = 0; nf < 4; ++nf)
#pragma unroll
                    for (int kk = 0; kk < 2; ++kk)
                        o[rb][nf] = __builtin_amdgcn_mfma_f32_16x16x32_bf16(
                            pa[kk], vf[nf][kk], o[rb][nf], 0, 0, 0);
            }
        }
        __syncthreads();
    }

#pragma unroll
    for (int rb = 0; rb < 2; ++rb)
#pragma unroll
        for (int nf = 0; nf < 4; ++nf)
#pragma unroll
            for (int i = 0; i < 4; ++i) {
                const float val = o[rb][nf][i] / lrun[rb][i];
                Y[(size_t)(b * T + wqbase + rb * 16 + rq + i) * DOUT + h * 64 + nf * 16 + fr] =
                    f2bf(val);
            }
}

extern "C" void kernel_launch(void* const* d_in, const int* in_sizes, int n_in,
                              void* d_out, int out_size, void* d_ws, size_t ws_size,
                              hipStream_t stream) {
    const float* x  = (const float*)d_in[0];
    const float* Wq = (const float*)d_in[1];
    const float* Wk = (const float*)d_in[2];
    const float* Wv = (const float*)d_in[3];
    const float* Wo = (const float*)d_in[4];

    constexpr int B = 4, T = 2048, D = 1024;
    constexpr int M = B * T;                 // 8192
    const int nx = in_sizes[0];              // 8388608
    const int nw = in_sizes[1];              // 1048576

    char* ws = (char*)d_ws;
    u16* xb   = (u16*)(ws);                                  // 16 MB
    u16* qkb  = (u16*)(ws + (16ull << 20));                  // 32 MB [8192][2048]
    u16* vtg  = (u16*)(ws + (48ull << 20));                  // 16 MB [4096][2048]
    u16* yb   = (u16*)(ws + (64ull << 20));                  // 16 MB
    u16* wqkv = (u16*)(ws + (80ull << 20));                  // 6 MB  [3072][1024]
    u16* wob  = (u16*)(ws + (86ull << 20));                  // 2 MB

    cast_f32_bf16<<<2048, 256, 0, stream>>>(x, xb, nx);
    cast_f32_bf16<<<512, 256, 0, stream>>>(Wq, wqkv, nw);
    cast_f32_bf16<<<512, 256, 0, stream>>>(Wk, wqkv + (size_t)nw, nw);
    cast_f32_bf16<<<512, 256, 0, stream>>>(Wv, wqkv + 2 * (size_t)nw, nw);
    cast_f32_bf16<<<512, 256, 0, stream>>>(Wo, wob, nw);

    gemm_bt<1><<<dim3(M / 128, 3072 / 128), 256, 0, stream>>>(xb, wqkv, qkb, vtg, M, 3072, D);

    attn_fwd<<<dim3(T / 128, B * 16), 256, 0, stream>>>(qkb, vtg, yb);

    gemm_bt<0><<<dim3(M / 128, D / 128), 256, 0, stream>>>(yb, wob, d_out, nullptr, M, D, D);
}

// Round 3
// 261.417 us; speedup vs baseline: 1.5556x; 1.4289x over previous
//
#include <hip/hip_runtime.h>
#include <cstdint>
#include <cstddef>

typedef unsigned short u16;
typedef short bf16x8 __attribute__((ext_vector_type(8)));
typedef unsigned short u16x8 __attribute__((ext_vector_type(8)));
typedef float f32x4 __attribute__((ext_vector_type(4)));

__device__ __forceinline__ u16 f2bf(float x) {
    union { float f; unsigned int u; } v; v.f = x;
    unsigned int u = v.u;
    unsigned int r = (u + 0x7fffu + ((u >> 16) & 1u)) >> 16;
    return (u16)r;
}

// async global->LDS, 16B per lane. dest = wave-uniform base; lane i lands at base + i*16B.
__device__ __forceinline__ void load_lds16(const void* g, void* l) {
    __builtin_amdgcn_global_load_lds((const __attribute__((address_space(1))) void*)g,
                                     (__attribute__((address_space(3))) void*)l, 16, 0, 0);
}

// ---------------- cast fp32 -> bf16 ----------------
__global__ void cast_f32_bf16(const float* __restrict__ in, u16* __restrict__ out, int n) {
    int i = (blockIdx.x * blockDim.x + threadIdx.x) * 4;
    int stride = gridDim.x * blockDim.x * 4;
    for (; i < n; i += stride) {
        float4 f = *reinterpret_cast<const float4*>(in + i);
        ushort4 o;
        o.x = f2bf(f.x); o.y = f2bf(f.y); o.z = f2bf(f.z); o.w = f2bf(f.w);
        *reinterpret_cast<ushort4*>(out + i) = o;
    }
}

// ---------------- bf16 GEMM: C[M,N] = A[M,K] @ B[N,K]^T ----------------
template <int MODE>
__global__ __launch_bounds__(256) void gemm_bt(const u16* __restrict__ A,
                                               const u16* __restrict__ Bw,
                                               void* __restrict__ outp,
                                               u16* __restrict__ vtg,
                                               int M, int N, int K) {
    __shared__ u16 smem[16384];
    u16* As = smem;
    u16* Bs = smem + 4096;

    const int tid  = threadIdx.x;
    const int m0   = blockIdx.x * 128;
    const int n0   = blockIdx.y * 128;
    const int wid  = tid >> 6;
    const int lane = tid & 63;
    const int wr   = (wid >> 1) * 64;
    const int wc   = (wid & 1) * 64;
    const int fr   = lane & 15;
    const int ko   = (lane >> 4) * 8;
    const int rq   = (lane >> 4) * 4;

    f32x4 acc[4][4];
#pragma unroll
    for (int i = 0; i < 4; ++i)
#pragma unroll
        for (int j = 0; j < 4; ++j) acc[i][j] = f32x4{0.f, 0.f, 0.f, 0.f};

    const int lr4 = lane >> 2;
    const int ls  = lane & 3;

    for (int k0 = 0; k0 < K; k0 += 32) {
#pragma unroll
        for (int t = 0; t < 2; ++t) {
            const int qtr = wid * 2 + t;
            const int r   = qtr * 16 + lr4;
            load_lds16(&A[(size_t)(m0 + r) * K + k0 + ls * 8], &As[qtr * 512]);
            load_lds16(&Bw[(size_t)(n0 + r) * K + k0 + ls * 8], &Bs[qtr * 512]);
        }
        __syncthreads();

        bf16x8 af[4], bfr[4];
#pragma unroll
        for (int mf = 0; mf < 4; ++mf)
            af[mf] = *reinterpret_cast<const bf16x8*>(&As[(wr + mf * 16 + fr) * 32 + ko]);
#pragma unroll
        for (int nf = 0; nf < 4; ++nf)
            bfr[nf] = *reinterpret_cast<const bf16x8*>(&Bs[(wc + nf * 16 + fr) * 32 + ko]);
        __builtin_amdgcn_s_setprio(1);
#pragma unroll
        for (int mf = 0; mf < 4; ++mf)
#pragma unroll
            for (int nf = 0; nf < 4; ++nf)
                acc[mf][nf] = __builtin_amdgcn_mfma_f32_16x16x32_bf16(
                    af[mf], bfr[nf], acc[mf][nf], 0, 0, 0);
        __builtin_amdgcn_s_setprio(0);
        __syncthreads();
    }

    if constexpr (MODE == 0) {
        float* C = (float*)outp;
#pragma unroll
        for (int mf = 0; mf < 4; ++mf)
#pragma unroll
            for (int nf = 0; nf < 4; ++nf)
#pragma unroll
                for (int i = 0; i < 4; ++i)
                    C[(size_t)(m0 + wr + mf * 16 + rq + i) * N + n0 + wc + nf * 16 + fr] =
                        acc[mf][nf][i];
    } else {
        if (n0 < 2048) {
            u16* qk = (u16*)outp;
#pragma unroll
            for (int mf = 0; mf < 4; ++mf)
#pragma unroll
                for (int nf = 0; nf < 4; ++nf)
#pragma unroll
                    for (int i = 0; i < 4; ++i)
                        qk[(size_t)(m0 + wr + mf * 16 + rq + i) * 2048 + n0 + wc + nf * 16 + fr] =
                            f2bf(acc[mf][nf][i]);
        } else {
            // transpose 128x128 tile through LDS (swizzled), write V^T
#pragma unroll
            for (int mf = 0; mf < 4; ++mf)
#pragma unroll
                for (int nf = 0; nf < 4; ++nf)
#pragma unroll
                    for (int i = 0; i < 4; ++i) {
                        const int nl = wc + nf * 16 + fr;
                        const int ml = wr + mf * 16 + rq + i;
                        smem[nl * 128 + ((((ml * 2) ^ ((nl & 15) << 4))) >> 1)] =
                            f2bf(acc[mf][nf][i]);
                    }
            __syncthreads();
            const int bb   = m0 >> 11;
            const int tloc = m0 & 2047;
#pragma unroll
            for (int p = 0; p < 8; ++p) {
                const int nl = (tid >> 4) + p * 16;
                const int sl = tid & 15;
                u16x8 v = *reinterpret_cast<const u16x8*>(
                    &smem[nl * 128 + ((((sl * 16) ^ ((nl & 15) << 4))) >> 1)]);
                *reinterpret_cast<u16x8*>(
                    &vtg[(size_t)(bb * 1024 + (n0 - 2048) + nl) * 2048 + tloc + sl * 8]) = v;
            }
        }
    }
}

// ---------------- causal flash attention ----------------
// qk: [B*T, 2048] bf16 (Q cols 0..1023, K cols 1024..2047), vtg: [B*16*64, 2048] = V^T per (b,h).
// grid (8, B*16): block j handles q-tiles {15-j, j} (balanced: 34 KV tiles each).
// Double-buffered K/V staging: prefetch tile kt+1 before computing kt; one barrier/tile.
__global__ __launch_bounds__(256) void attn_fwd(const u16* __restrict__ qk,
                                                const u16* __restrict__ vtg,
                                                u16* __restrict__ Y) {
    constexpr int T = 2048, DQK = 2048, DOUT = 1024;
    const int jb = blockIdx.x;            // 0..7
    const int bh = blockIdx.y;
    const int b  = bh >> 4, h = bh & 15;
    const int tid = threadIdx.x, w = tid >> 6, lane = tid & 63;

    __shared__ u16 Ks[2][4096];   // [64 k][64 d] linear, slot^(row&7) swizzle
    __shared__ u16 Vs[2][4096];   // [64 d][64 k] linear, same swizzle
    __shared__ u16 Ps[8192];      // per-wave P staging, swizzled rows

    const int fr = lane & 15, g = lane >> 4;
    const int ko = g * 8, rq = g * 4;
    const int sr8 = lane >> 3, ss = lane & 7;
    constexpr float SCL = 1.4426950408889634f * 0.125f;   // log2(e)/sqrt(64)

    const size_t rowb = (size_t)b * T;

    for (int qi = 0; qi < 2; ++qi) {
        const int qt = (qi == 0) ? (15 - jb) : jb;
        const int q0 = qt * 128;
        const int wqbase = q0 + w * 32;
        const int NT = 2 * qt + 2;

        bf16x8 qf[2][2];
#pragma unroll
        for (int rb = 0; rb < 2; ++rb)
#pragma unroll
            for (int kk = 0; kk < 2; ++kk)
                qf[rb][kk] = *reinterpret_cast<const bf16x8*>(
                    &qk[(rowb + wqbase + rb * 16 + fr) * DQK + h * 64 + kk * 32 + ko]);

        f32x4 o[2][4];
        float mrun[2][4], lrun[2][4];
#pragma unroll
        for (int rb = 0; rb < 2; ++rb)
#pragma unroll
            for (int nf = 0; nf < 4; ++nf) o[rb][nf] = f32x4{0.f, 0.f, 0.f, 0.f};
#pragma unroll
        for (int rb = 0; rb < 2; ++rb)
#pragma unroll
            for (int i = 0; i < 4; ++i) { mrun[rb][i] = -INFINITY; lrun[rb][i] = 0.f; }

        // protect K/V buffers from the previous q-tile's in-flight compute
        __syncthreads();

        // prologue: stage tile 0 into buf 0
        {
            const int qtr = w * 2, r0 = qtr * 8 + sr8, r1 = r0 + 8;
            const int sc0 = (ss ^ (r0 & 7)) * 8, sc1 = (ss ^ (r1 & 7)) * 8;
            load_lds16(&qk[(rowb + r0) * DQK + 1024 + h * 64 + sc0], &Ks[0][qtr * 512]);
            load_lds16(&vtg[((size_t)bh * 64 + r0) * T + sc0], &Vs[0][qtr * 512]);
            load_lds16(&qk[(rowb + r1) * DQK + 1024 + h * 64 + sc1], &Ks[0][(qtr + 1) * 512]);
            load_lds16(&vtg[((size_t)bh * 64 + r1) * T + sc1], &Vs[0][(qtr + 1) * 512]);
        }

        for (int kt = 0; kt < NT; ++kt) {
            __syncthreads();   // drains stage(kt); all waves done with compute(kt-1)

            if (kt + 1 < NT) {
                const int nb = (kt + 1) & 1;
                const int k0n = (kt + 1) * 64;
                const int qtr = w * 2, r0 = qtr * 8 + sr8, r1 = r0 + 8;
                const int sc0 = (ss ^ (r0 & 7)) * 8, sc1 = (ss ^ (r1 & 7)) * 8;
                load_lds16(&qk[(rowb + k0n + r0) * DQK + 1024 + h * 64 + sc0], &Ks[nb][qtr * 512]);
                load_lds16(&vtg[((size_t)bh * 64 + r0) * T + k0n + sc0], &Vs[nb][qtr * 512]);
                load_lds16(&qk[(rowb + k0n + r1) * DQK + 1024 + h * 64 + sc1], &Ks[nb][(qtr + 1) * 512]);
                load_lds16(&vtg[((size_t)bh * 64 + r1) * T + k0n + sc1], &Vs[nb][(qtr + 1) * 512]);
            }

            const int k0 = kt * 64;
            if (k0 <= wqbase + 31) {   // wave-uniform skip of fully-masked tiles
                const u16* Kb = Ks[kt & 1];
                const u16* Vb = Vs[kt & 1];

                bf16x8 kf[4][2];
#pragma unroll
                for (int nf = 0; nf < 4; ++nf)
#pragma unroll
                    for (int kk = 0; kk < 2; ++kk) {
                        const int r = nf * 16 + fr;
                        kf[nf][kk] = *reinterpret_cast<const bf16x8*>(
                            &Kb[r * 64 + ((((g + kk * 4) * 16) ^ ((r & 7) << 4)) >> 1)]);
                    }
                f32x4 s[2][4];
#pragma unroll
                for (int rb = 0; rb < 2; ++rb)
#pragma unroll
                    for (int nf = 0; nf < 4; ++nf) s[rb][nf] = f32x4{0.f, 0.f, 0.f, 0.f};
                __builtin_amdgcn_s_setprio(1);
#pragma unroll
                for (int rb = 0; rb < 2; ++rb)
#pragma unroll
                    for (int nf = 0; nf < 4; ++nf)
#pragma unroll
                        for (int kk = 0; kk < 2; ++kk)
                            s[rb][nf] = __builtin_amdgcn_mfma_f32_16x16x32_bf16(
                                qf[rb][kk], kf[nf][kk], s[rb][nf], 0, 0, 0);
                __builtin_amdgcn_s_setprio(0);

                float fsc[2][4];
#pragma unroll
                for (int rb = 0; rb < 2; ++rb) {
                    const int rbase = wqbase + rb * 16;
                    const bool dm = (k0 + 63 > rbase);
                    float pm[4] = {-1e30f, -1e30f, -1e30f, -1e30f};
#pragma unroll
                    for (int nf = 0; nf < 4; ++nf)
#pragma unroll
                        for (int i = 0; i < 4; ++i) {
                            float sv = s[rb][nf][i] * SCL;
                            if (dm) {
                                const int kc = k0 + nf * 16 + fr;
                                const int qr = rbase + rq + i;
                                if (kc > qr) sv = -1e30f;
                            }
                            s[rb][nf][i] = sv;
                            pm[i] = fmaxf(pm[i], sv);
                        }
#pragma unroll
                    for (int mask = 1; mask < 16; mask <<= 1)
#pragma unroll
                        for (int i = 0; i < 4; ++i) pm[i] = fmaxf(pm[i], __shfl_xor(pm[i], mask));

                    float mn[4], ps[4];
#pragma unroll
                    for (int i = 0; i < 4; ++i) {
                        mn[i]       = fmaxf(mrun[rb][i], pm[i]);
                        fsc[rb][i]  = exp2f(mrun[rb][i] - mn[i]);
                        mrun[rb][i] = mn[i];
                        ps[i]       = 0.f;
                    }
#pragma unroll
                    for (int nf = 0; nf < 4; ++nf)
#pragma unroll
                        for (int i = 0; i < 4; ++i) {
                            float p = exp2f(s[rb][nf][i] - mn[i]);
                            s[rb][nf][i] = p;
                            ps[i] += p;
                        }
#pragma unroll
                    for (int mask = 1; mask < 16; mask <<= 1)
#pragma unroll
                        for (int i = 0; i < 4; ++i) ps[i] += __shfl_xor(ps[i], mask);
#pragma unroll
                    for (int i = 0; i < 4; ++i) lrun[rb][i] = lrun[rb][i] * fsc[rb][i] + ps[i];

                    u16* pw = &Ps[(w * 2 + rb) * 1024];
#pragma unroll
                    for (int nf = 0; nf < 4; ++nf)
#pragma unroll
                        for (int i = 0; i < 4; ++i) {
                            const int r = rq + i, c = nf * 16 + fr;
                            pw[r * 64 + ((((c * 2) ^ ((r & 7) << 4))) >> 1)] = f2bf(s[rb][nf][i]);
                        }
#pragma unroll
                    for (int nf = 0; nf < 4; ++nf)
#pragma unroll
                        for (int i = 0; i < 4; ++i) o[rb][nf][i] *= fsc[rb][i];
                }

                bf16x8 vf[4][2];
#pragma unroll
                for (int nf = 0; nf < 4; ++nf)
#pragma unroll
                    for (int kk = 0; kk < 2; ++kk) {
                        const int r = nf * 16 + fr;
                        vf[nf][kk] = *reinterpret_cast<const bf16x8*>(
                            &Vb[r * 64 + ((((g + kk * 4) * 16) ^ ((r & 7) << 4)) >> 1)]);
                    }
#pragma unroll
                for (int rb = 0; rb < 2; ++rb) {
                    const u16* pr = &Ps[(w * 2 + rb) * 1024];
                    bf16x8 pa[2];
#pragma unroll
                    for (int kk = 0; kk < 2; ++kk)
                        pa[kk] = *reinterpret_cast<const bf16x8*>(
                            &pr[fr * 64 + ((((g + kk * 4) * 16) ^ ((fr & 7) << 4)) >> 1)]);
                    __builtin_amdgcn_s_setprio(1);
#pragma unroll
                    for (int nf = 0; nf < 4; ++nf)
#pragma unroll
                        for (int kk = 0; kk < 2; ++kk)
                            o[rb][nf] = __builtin_amdgcn_mfma_f32_16x16x32_bf16(
                                pa[kk], vf[nf][kk], o[rb][nf], 0, 0, 0);
                    __builtin_amdgcn_s_setprio(0);
                }
            }
        }

#pragma unroll
        for (int rb = 0; rb < 2; ++rb)
#pragma unroll
            for (int nf = 0; nf < 4; ++nf)
#pragma unroll
                for (int i = 0; i < 4; ++i) {
                    const float val = o[rb][nf][i] / lrun[rb][i];
                    Y[(rowb + wqbase + rb * 16 + rq + i) * DOUT + h * 64 + nf * 16 + fr] =
                        f2bf(val);
                }
    }
}

extern "C" void kernel_launch(void* const* d_in, const int* in_sizes, int n_in,
                              void* d_out, int out_size, void* d_ws, size_t ws_size,
                              hipStream_t stream) {
    const float* x  = (const float*)d_in[0];
    const float* Wq = (const float*)d_in[1];
    const float* Wk = (const float*)d_in[2];
    const float* Wv = (const float*)d_in[3];
    const float* Wo = (const float*)d_in[4];

    constexpr int B = 4, T = 2048, D = 1024;
    constexpr int M = B * T;
    const int nx = in_sizes[0];
    const int nw = in_sizes[1];

    char* ws = (char*)d_ws;
    u16* xb   = (u16*)(ws);
    u16* qkb  = (u16*)(ws + (16ull << 20));
    u16* vtg  = (u16*)(ws + (48ull << 20));
    u16* yb   = (u16*)(ws + (64ull << 20));
    u16* wqkv = (u16*)(ws + (80ull << 20));
    u16* wob  = (u16*)(ws + (86ull << 20));

    cast_f32_bf16<<<2048, 256, 0, stream>>>(x, xb, nx);
    cast_f32_bf16<<<512, 256, 0, stream>>>(Wq, wqkv, nw);
    cast_f32_bf16<<<512, 256, 0, stream>>>(Wk, wqkv + (size_t)nw, nw);
    cast_f32_bf16<<<512, 256, 0, stream>>>(Wv, wqkv + 2 * (size_t)nw, nw);
    cast_f32_bf16<<<512, 256, 0, stream>>>(Wo, wob, nw);

    gemm_bt<1><<<dim3(M / 128, 3072 / 128), 256, 0, stream>>>(xb, wqkv, qkb, vtg, M, 3072, D);

    attn_fwd<<<dim3(8, B * 16), 256, 0, stream>>>(qkb, vtg, yb);

    gemm_bt<0><<<dim3(M / 128, D / 128), 256, 0, stream>>>(yb, wob, d_out, nullptr, M, D, D);
}